// Round 6
// baseline (184.411 us; speedup 1.0000x reference)
//
#include <hip/hip_runtime.h>

#define B_TOT 65536
#define R 12
#define L 16
#define NB 8            // batches per block (128 threads, 2 waves)
#define NEG_MIN -3.402823466e38f

// ws layout (float index):
//   [0,32)   v[j]            (legacy, folded into table B)
//   [32]     c               (legacy, folded into Bu)
//   [40,52)  pmask (int: bit l set if freq_mask[r][l] != 0)
//   [64,96)  sorted breakpoints
//   [96,96+33*72) interval table row m: [0,32)=A  [32]=Au  [36,68)=B'=B+v  [68]=Bu'=Bu+c
//   [2472,2728) kw1 B-fragment (bf16 shorts): lane*8+kappa, k=(lane>>5)*8+kappa,
//               j=lane&31; k<11 -> kw1[k][j], k==11 -> kb1[j], else 0
#define WS_V   0
#define WS_C   32
#define WS_PM  40
#define WS_BP  64
#define WS_TAB 96
#define TROW   72
#define WS_KW  2472

// LDS short strides
#define TTF_BSTR 520   // 1040 B per batch (bank-rotated by 4)
#define BHF_BSTR 576   // 1152 B per batch; row (kb,l) at kb*136 + l*8 shorts (kb-padded)

typedef __attribute__((ext_vector_type(8)))  short short8;
typedef __attribute__((ext_vector_type(4)))  float f32x4;
typedef __attribute__((ext_vector_type(16))) float f32x16;

static __device__ __forceinline__ short f2bf(float f) {
    uint32_t u = __float_as_uint(f);
    uint32_t r = u + 0x7FFFu + ((u >> 16) & 1u);
    return (short)(r >> 16);
}
// pack two floats -> two bf16 in one int (lo = f0, hi = f1), RNE
static __device__ __forceinline__ int pack2(float f0, float f1) {
    uint32_t u0 = __float_as_uint(f0), u1 = __float_as_uint(f1);
    uint32_t r0 = u0 + 0x7FFFu + ((u0 >> 16) & 1u);
    uint32_t r1 = u1 + 0x7FFFu + ((u1 >> 16) & 1u);
    return (int)((r0 >> 16) | (r1 & 0xFFFF0000u));
}

__global__ __launch_bounds__(256) void nfh_pre(
    const float* __restrict__ qw1, const float* __restrict__ qb1,
    const float* __restrict__ qw2, const float* __restrict__ qb2,
    const float* __restrict__ kw1, const float* __restrict__ kb1,
    const float* __restrict__ kw2, const float* __restrict__ kb2,
    const int*   __restrict__ fmask,
    float* __restrict__ ws)
{
    __shared__ float sM[1024];
    __shared__ float su[32], sv[32];
    __shared__ float sw1[32], sb1[32], sbp[32];
    __shared__ float scc[1];
    const int t = threadIdx.x;

    if (t < 32) { sw1[t] = qw1[t]; sb1[t] = qb1[t]; }
    for (int e = t; e < 1024; e += 256) {
        const int i = e >> 5, j = e & 31;
        float acc = 0.f;
        for (int h = 0; h < 64; ++h) acc = fmaf(qw2[i * 64 + h], kw2[j * 64 + h], acc);
        sM[e] = acc;
    }
    if (t < 32) {
        float au = 0.f, av = 0.f;
        for (int h = 0; h < 64; ++h) {
            au = fmaf(qw2[t * 64 + h], kb2[h], au);
            av = fmaf(kw2[t * 64 + h], qb2[h], av);
        }
        su[t] = au;
        sv[t] = av;
        ws[WS_V + t] = av;
        const float w = qw1[t];
        sbp[t] = (w != 0.f) ? (-qb1[t] / w) : 3.0e30f;
    }
    if (t == 64) {
        float acc = 0.f;
        for (int h = 0; h < 64; ++h) acc = fmaf(qb2[h], kb2[h], acc);
        ws[WS_C] = acc;
        scc[0] = acc;
    }
    if (t < 12) {
        int pm = 0;
        for (int l = 0; l < 16; ++l) if (fmask[t * 16 + l] != 0) pm |= (1 << l);
        ((int*)ws)[WS_PM + t] = pm;
    }
    // kw1 B-fragment for the MLP MFMA (with kb1 as the k=11 row)
    if (t < 64) {
        const int j = t & 31;
        int w4[4];
        #pragma unroll
        for (int q = 0; q < 4; ++q) {
            float v0, v1;
            const int k0 = (t >> 5) * 8 + q * 2, k1 = k0 + 1;
            v0 = (k0 < 11) ? kw1[k0 * 32 + j] : ((k0 == 11) ? kb1[j] : 0.f);
            v1 = (k1 < 11) ? kw1[k1 * 32 + j] : ((k1 == 11) ? kb1[j] : 0.f);
            w4[q] = pack2(v0, v1);
        }
        int* wp = (int*)ws + WS_KW + t * 4;
        wp[0] = w4[0]; wp[1] = w4[1]; wp[2] = w4[2]; wp[3] = w4[3];
    }
    __syncthreads();
    if (t == 0) {
        for (int i = 1; i < 32; ++i) {
            float key = sbp[i]; int j = i - 1;
            while (j >= 0 && sbp[j] > key) { sbp[j + 1] = sbp[j]; --j; }
            sbp[j + 1] = key;
        }
    }
    __syncthreads();
    if (t < 32) ws[WS_BP + t] = sbp[t];

    for (int task = t; task < 33 * 32 + 33; task += 256) {
        const int m = (task < 33 * 32) ? (task >> 5) : (task - 33 * 32);
        const float xi = (m == 0) ? sbp[0] - 1.f
                       : ((m == 32) ? sbp[31] + 1.f
                                    : sbp[m - 1] + 0.5f * (sbp[m] - sbp[m - 1]));
        if (task < 33 * 32) {
            const int j = task & 31;
            float A = 0.f, Bv = 0.f;
            for (int i = 0; i < 32; ++i) {
                if (fmaf(sw1[i], xi, sb1[i]) > 0.f) {
                    A  = fmaf(sw1[i], sM[i * 32 + j], A);
                    Bv = fmaf(sb1[i], sM[i * 32 + j], Bv);
                }
            }
            ws[WS_TAB + m * TROW + j] = A;
            ws[WS_TAB + m * TROW + 36 + j] = Bv + sv[j];   // fold v
        } else {
            float Au = 0.f, Bu = 0.f;
            for (int i = 0; i < 32; ++i) {
                if (fmaf(sw1[i], xi, sb1[i]) > 0.f) {
                    Au = fmaf(sw1[i], su[i], Au);
                    Bu = fmaf(sb1[i], su[i], Bu);
                }
            }
            ws[WS_TAB + m * TROW + 32] = Au;
            ws[WS_TAB + m * TROW + 36 + 32] = Bu + scc[0]; // fold c
        }
    }
}

__global__ __launch_bounds__(128) void nfh_main(
    const float* __restrict__ rss,   // [B,R]
    const float* __restrict__ feat,  // [B,L,F]
    const float* __restrict__ pos,   // [B,L,3]
    const float* __restrict__ prev,  // [B,3]
    const float* __restrict__ gw1, const float* __restrict__ gb1,
    const float* __restrict__ gw2, const float* __restrict__ gb2,
    const float* __restrict__ sigma_p,
    const float* __restrict__ ws,
    float* __restrict__ out)
{
    // s_inf: MLP A-frags, pair p: lane(kb*32+m)*8 shorts; m=(bb&1)*16+l, K=16
    __shared__ short s_inf[(NB / 2) * 512];   // 4 KB
    __shared__ short s_bhf[NB * BHF_BSTR];    // 9 KB  score A-frags (bf16 bh)
    __shared__ short s_ttf[NB * TTF_BSTR];    // 8.1 KB score B-frags (bf16 tt')
    __shared__ float s_dsq[NB * 16];          // -dsq/(2s^2)
    __shared__ float s_tc[NB * 16];
    __shared__ int   s_pm[16];

    const int t = threadIdx.x;
    const int b0 = blockIdx.x * NB;
    const float sigma = sigma_p[0];
    const float inv2s2 = 1.f / (2.f * sigma * sigma);

    if (t < 16) s_pm[t] = (t < 12) ? ((const int*)ws)[WS_PM + t] : 0;

    // ---------- Ph0a: all 128 threads = (bb,l): stage led_input as bf16 A-frag ----
    {
        const int bb = t >> 4, l = t & 15;
        const int b = b0 + bb;
        const int p = bb >> 1, m = (bb & 1) * 16 + l;
        const float4* f4 = (const float4*)(feat + ((size_t)b * (L * 8) + l * 8));
        const float4 fa = f4[0], fb = f4[1];
        const float* pp = pos + ((size_t)b * (L * 3) + l * 3);
        const float p0 = pp[0], p1 = pp[1], p2 = pp[2];

        float dsq = 0.f;
        {
            float d0 = prev[b * 3 + 0] - p0, d1 = prev[b * 3 + 1] - p1, d2 = prev[b * 3 + 2] - p2;
            dsq = fmaf(d0, d0, fmaf(d1, d1, d2 * d2));
        }
        s_dsq[bb * 16 + l] = -dsq * inv2s2;

        int4 w0, w1;
        w0.x = pack2(fa.x, fa.y); w0.y = pack2(fa.z, fa.w);
        w0.z = pack2(fb.x, fb.y); w0.w = pack2(fb.z, fb.w);
        w1.x = pack2(p0, p1);     w1.y = pack2(p2, 1.0f);   // k=11 is the bias column
        w1.z = 0;                 w1.w = 0;
        *(int4*)&s_inf[p * 512 + m * 8]        = w0;  // kb=0 (k 0..7)
        *(int4*)&s_inf[p * 512 + (32 + m) * 8] = w1;  // kb=1 (k 8..15)
    }

    // ---------- Ph0b: t < 96 = (bb,r): gate -> iw, tt' lookup -> bf16 B-frag ------
    if (t < NB * R) {
        const int bb2 = t / R;
        const int r2 = t - bb2 * R;
        const float x = rss[(size_t)b0 * R + t];
        float z = gb2[0];
        #pragma unroll
        for (int i = 0; i < 16; ++i) {
            const float h = fmaxf(fmaf(x, gw1[i], gb1[i]), 0.f);
            z = fmaf(h, gw2[i], z);
        }
        const float gate = 1.f / (1.f + __expf(-z));
        const float iw = (x > 0.5f) ? gate : 0.f;
        out[(size_t)B_TOT * R * L + (size_t)b0 * R + t] = iw;
        const float xq = x * iw;

        int k = 0;
        #pragma unroll
        for (int m = 0; m < 32; ++m) k += (xq > ws[WS_BP + m]) ? 1 : 0;
        const float* row = ws + WS_TAB + k * TROW;
        const float4* ra = (const float4*)row;
        const float4* rb = (const float4*)(row + 36);
        s_tc[bb2 * 16 + r2] = fmaf(xq, row[32], row[68]);   // Au*xq + (Bu + c)
        #pragma unroll
        for (int kb = 0; kb < 4; ++kb) {
            const float4 a0 = ra[kb * 2], b0_ = rb[kb * 2];
            const float4 a1 = ra[kb * 2 + 1], b1_ = rb[kb * 2 + 1];
            int4 pk;
            pk.x = pack2(fmaf(xq, a0.x, b0_.x), fmaf(xq, a0.y, b0_.y));
            pk.y = pack2(fmaf(xq, a0.z, b0_.z), fmaf(xq, a0.w, b0_.w));
            pk.z = pack2(fmaf(xq, a1.x, b1_.x), fmaf(xq, a1.y, b1_.y));
            pk.w = pack2(fmaf(xq, a1.z, b1_.z), fmaf(xq, a1.w, b1_.w));
            *(int4*)&s_ttf[bb2 * TTF_BSTR + (kb * 16 + r2) * 8] = pk;
        }
    } else {
        // t in [96,128): zero B-frag rows r=12..15
        const int u = t - 96;
        const int bb = u >> 2, r = 12 + (u & 3);
        const int4 z4 = {0, 0, 0, 0};
        #pragma unroll
        for (int kb = 0; kb < 4; ++kb)
            *(int4*)&s_ttf[bb * TTF_BSTR + (kb * 16 + r) * 8] = z4;
        s_tc[bb * 16 + r] = 0.f;
    }
    __syncthreads();

    // ---------- Ph1: wave w: MLP MFMA for pairs p = 2w, 2w+1 ----------
    {
        const int lane = t & 63;
        const int w = t >> 6;
        const int j = lane & 31;
        const int jk = (j >> 3) * 136 + (j & 7);  // bhf column offset (kb-padded)
        const short8 bfk = *(const short8*)((const int*)ws + WS_KW + lane * 4);

        #pragma unroll
        for (int pp = 0; pp < 2; ++pp) {
            const int p = w * 2 + pp;
            const short8 af = *(const short8*)&s_inf[p * 512 + lane * 8];
            f32x16 acc = {0.f,0.f,0.f,0.f,0.f,0.f,0.f,0.f,0.f,0.f,0.f,0.f,0.f,0.f,0.f,0.f};
            acc = __builtin_amdgcn_mfma_f32_32x32x16_bf16(af, bfk, acc, 0, 0, 0);
            #pragma unroll
            for (int rg = 0; rg < 16; ++rg) {
                const int rrow = (rg & 3) + 8 * (rg >> 2) + 4 * (lane >> 5);
                const int l = rrow & 15;
                const int bb = p * 2 + (rrow >> 4);
                s_bhf[bb * BHF_BSTR + l * 8 + jk] = f2bf(fmaxf(acc[rg], 0.f));
            }
        }
    }
    __syncthreads();

    // ---------- P3: wave w: score MFMA + softmax for batches w*4 .. w*4+3 --------
    {
        const int lane = t & 63;
        const int w = t >> 6;
        const int r = lane & 15;
        const int lg = lane >> 4;
        const int pm = s_pm[r];
        const int aoff = lg * 272 + (lane & 15) * 8;  // (kb=lg)*136*2? no: kb*136 + l*8 shorts
        // NOTE: for the score A-frag, lane = kb*16 + l: kb = lane>>4 (=lg), l = lane&15 (=r var!)
        // byte layout: kb*136 + l*8 shorts
        const int a_sh = (lane >> 4) * 136 + (lane & 15) * 8;

        #pragma unroll
        for (int i = 0; i < 4; ++i) {
            const int bb = w * 4 + i;
            const short8 af = *(const short8*)&s_bhf[bb * BHF_BSTR + a_sh];
            const short8 bf = *(const short8*)&s_ttf[bb * TTF_BSTR + lane * 8];
            f32x4 acc = {0.f, 0.f, 0.f, 0.f};
            acc = __builtin_amdgcn_mfma_f32_16x16x32_bf16(af, bf, acc, 0, 0, 0);

            const float tc = s_tc[bb * 16 + r];
            const f32x4 d4 = *(const f32x4*)&s_dsq[bb * 16 + lg * 4];

            float sc[4];
            #pragma unroll
            for (int jj = 0; jj < 4; ++jj) {
                sc[jj] = acc[jj] + tc + d4[jj];
                if (!((pm >> (lg * 4 + jj)) & 1)) sc[jj] = NEG_MIN;
            }
            float mx = fmaxf(fmaxf(sc[0], sc[1]), fmaxf(sc[2], sc[3]));
            mx = fmaxf(mx, __shfl_xor(mx, 16));
            mx = fmaxf(mx, __shfl_xor(mx, 32));
            float sum = 0.f;
            #pragma unroll
            for (int jj = 0; jj < 4; ++jj) { sc[jj] = __expf(sc[jj] - mx); sum += sc[jj]; }
            sum += __shfl_xor(sum, 16);
            sum += __shfl_xor(sum, 32);
            const float inv = 1.f / sum;

            if (r < R) {
                float4* op = (float4*)(out + ((size_t)(b0 + bb) * R + r) * L + lg * 4);
                *op = make_float4(sc[0] * inv, sc[1] * inv, sc[2] * inv, sc[3] * inv);
            }
        }
        (void)aoff;
    }
}

extern "C" void kernel_launch(void* const* d_in, const int* in_sizes, int n_in,
                              void* d_out, int out_size, void* d_ws, size_t ws_size,
                              hipStream_t stream) {
    const float* rss   = (const float*)d_in[0];
    const float* feat  = (const float*)d_in[1];
    const float* pos   = (const float*)d_in[2];
    const float* prev  = (const float*)d_in[3];
    const int*   fmask = (const int*)d_in[4];
    const float* gw1   = (const float*)d_in[5];
    const float* gb1   = (const float*)d_in[6];
    const float* gw2   = (const float*)d_in[7];
    const float* gb2   = (const float*)d_in[8];
    const float* qw1   = (const float*)d_in[9];
    const float* qb1   = (const float*)d_in[10];
    const float* qw2   = (const float*)d_in[11];
    const float* qb2   = (const float*)d_in[12];
    const float* kw1   = (const float*)d_in[13];
    const float* kb1   = (const float*)d_in[14];
    const float* kw2   = (const float*)d_in[15];
    const float* kb2   = (const float*)d_in[16];
    const float* sigma = (const float*)d_in[17];
    float* out = (float*)d_out;
    float* ws  = (float*)d_ws;

    nfh_pre<<<1, 256, 0, stream>>>(qw1, qb1, qw2, qb2, kw1, kb1, kw2, kb2, fmask, ws);
    nfh_main<<<B_TOT / NB, 128, 0, stream>>>(
        rss, feat, pos, prev,
        gw1, gb1, gw2, gb2,
        sigma, ws, out);
}